// Round 1
// baseline (627.416 us; speedup 1.0000x reference)
//
#include <hip/hip_runtime.h>

// Problem constants (B,T,HID)=(4,2048,2048), heads 16, kv 2, hd 128.
#define B_    4
#define T_    2048
#define HID_  2048
#define NH_   16
#define NKV_  2
#define HD_   128
#define M_    (B_ * T_)      // 8192 rows
#define NQKV_ 2560           // 16*128 + 2*128 + 2*128

typedef __bf16 bf16x8 __attribute__((ext_vector_type(8)));
typedef float  f32x4  __attribute__((ext_vector_type(4)));

#define AS1 __attribute__((address_space(1)))
#define AS3 __attribute__((address_space(3)))

// async global->LDS, 16B per lane; LDS dest = wave-uniform base + lane*16
__device__ __forceinline__ void load_lds16(const void* g, void* l) {
  __builtin_amdgcn_global_load_lds((const AS1 unsigned int*)g,
                                   (AS3 unsigned int*)l, 16, 0, 0);
}

__device__ __forceinline__ unsigned short f2bf(float x) {
  union { float f; unsigned u; } a; a.f = x;
  unsigned r = a.u + 0x7fffu + ((a.u >> 16) & 1u);   // RNE
  return (unsigned short)(r >> 16);
}
__device__ __forceinline__ float bf2f(unsigned h) {
  union { unsigned u; float f; } a; a.u = h << 16;
  return a.f;
}

// ---------------- cast f32 -> bf16 (4 elems/thread) ----------------
__global__ __launch_bounds__(256) void cast_bf16(const float* __restrict__ in,
                                                 unsigned short* __restrict__ out,
                                                 int n4) {
  int i = blockIdx.x * 256 + threadIdx.x;
  if (i >= n4) return;
  float4 v = ((const float4*)in)[i];
  ushort4 o;
  o.x = f2bf(v.x); o.y = f2bf(v.y); o.z = f2bf(v.z); o.w = f2bf(v.w);
  ((ushort4*)out)[i] = o;
}

// ---------------- GEMM C = A * B^T (A: MxK row-major bf16, B: NxK row-major bf16)
// m97-style: 128x128 tile, BK=32, global_load_lds w16, 4 waves x 4x4 mfma tiles.
template <int OUT_BF16>
__global__ __launch_bounds__(256) void gemm_bt(const unsigned short* __restrict__ A,
                                               const unsigned short* __restrict__ Bm,
                                               void* __restrict__ C,
                                               int M, int N, int K) {
  __shared__ __align__(16) unsigned short As[128 * 32];
  __shared__ __align__(16) unsigned short Bs[128 * 32];
  const int tid = threadIdx.x;
  const int w = tid >> 6, lane = tid & 63;
  const int m0 = blockIdx.y << 7, n0 = blockIdx.x << 7;
  const int c = lane & 15, grp = lane >> 4;
  const int lr = lane >> 2, lc = (lane & 3) << 3;   // staging: 4 lanes/row of 32 bf16
  const int wm = (w & 1) << 6, wn = (w >> 1) << 6;  // 64x64 per wave
  f32x4 acc[4][4] = {};
  for (int k0 = 0; k0 < K; k0 += 32) {
    __syncthreads();
    {
      int r0 = w << 4;  // wave w stages rows [w*16, w*16+16) and +64
      load_lds16(A + (size_t)(m0 + r0 + lr) * K + k0 + lc, &As[r0 * 32]);
      load_lds16(A + (size_t)(m0 + 64 + r0 + lr) * K + k0 + lc, &As[(64 + r0) * 32]);
      load_lds16(Bm + (size_t)(n0 + r0 + lr) * K + k0 + lc, &Bs[r0 * 32]);
      load_lds16(Bm + (size_t)(n0 + 64 + r0 + lr) * K + k0 + lc, &Bs[(64 + r0) * 32]);
    }
    __syncthreads();
    bf16x8 af[4], bf[4];
#pragma unroll
    for (int i = 0; i < 4; i++)
      af[i] = *(const bf16x8*)&As[(wm + i * 16 + c) * 32 + grp * 8];
#pragma unroll
    for (int j = 0; j < 4; j++)
      bf[j] = *(const bf16x8*)&Bs[(wn + j * 16 + c) * 32 + grp * 8];
#pragma unroll
    for (int i = 0; i < 4; i++)
#pragma unroll
      for (int j = 0; j < 4; j++)
        acc[i][j] = __builtin_amdgcn_mfma_f32_16x16x32_bf16(af[i], bf[j], acc[i][j], 0, 0, 0);
  }
#pragma unroll
  for (int i = 0; i < 4; i++)
#pragma unroll
    for (int j = 0; j < 4; j++)
#pragma unroll
      for (int r = 0; r < 4; r++) {
        int row = m0 + wm + i * 16 + grp * 4 + r;   // C/D: row=(lane>>4)*4+reg
        int col = n0 + wn + j * 16 + c;             //      col=lane&15
        float v = acc[i][j][r];
        if (OUT_BF16) ((unsigned short*)C)[(size_t)row * N + col] = f2bf(v);
        else          ((float*)C)[(size_t)row * N + col] = v;
      }
}

// ---------------- RoPE + RMSNorm. One wave per head per (b,t): lane i owns pair (2i,2i+1).
__global__ __launch_bounds__(256) void rope_norm(const unsigned short* __restrict__ qkv,
                                                 const float* __restrict__ cosb,
                                                 const float* __restrict__ sinb,
                                                 unsigned short* __restrict__ qo,
                                                 unsigned short* __restrict__ ko,
                                                 unsigned short* __restrict__ vo) {
  const int m = blockIdx.x;
  const int b = m >> 11, t = m & 2047;
  const int w = threadIdx.x >> 6, lane = threadIdx.x & 63;
  const float cv = cosb[t * 64 + lane], sv = sinb[t * 64 + lane];
  const unsigned short* row = qkv + (size_t)m * NQKV_;
  for (int hh = w; hh < 20; hh += 4) {
    if (hh < 18) {
      const int col0 = (hh < 16) ? hh * 128 : 2048 + (hh - 16) * 128;
      unsigned pr = *(const unsigned*)(row + col0 + 2 * lane);
      float xr = bf2f(pr & 0xffffu), xi = bf2f(pr >> 16);
      float orr = xr * cv - xi * sv;
      float oi  = xr * sv + xi * cv;
      float ss = orr * orr + oi * oi;
#pragma unroll
      for (int off = 1; off < 64; off <<= 1) ss += __shfl_xor(ss, off);
      float scl = rsqrtf(ss * (1.0f / 128.0f) + 1.1920929e-07f);  // fp32 eps
      unsigned out = (unsigned)f2bf(orr * scl) | ((unsigned)f2bf(oi * scl) << 16);
      if (hh < 16)
        *(unsigned*)(qo + (((size_t)(b * NH_ + hh)) * T_ + t) * HD_ + 2 * lane) = out;
      else
        *(unsigned*)(ko + (((size_t)(b * NKV_ + (hh - 16))) * T_ + t) * HD_ + 2 * lane) = out;
    } else {
      const int gg = hh - 18;
      unsigned pr = *(const unsigned*)(row + 2304 + gg * 128 + 2 * lane);
      *(unsigned*)(vo + (((size_t)(b * NKV_ + gg)) * T_ + t) * HD_ + 2 * lane) = pr;
    }
  }
}

// ---------------- V transpose: (bg, T, HD) -> (bg, HD, T), 64x64 LDS tiles
__global__ __launch_bounds__(256) void transpose_v(const unsigned short* __restrict__ v,
                                                   unsigned short* __restrict__ vt) {
  __shared__ unsigned short tile[64][65];
  const int bg = blockIdx.z;
  const int t0 = blockIdx.x << 6, h0 = blockIdx.y << 6;
  const unsigned short* src = v + (size_t)bg * T_ * HD_;
  unsigned short* dst = vt + (size_t)bg * T_ * HD_;
  const int tid = threadIdx.x;
  const int rr = tid >> 4, cc = (tid & 15) << 2;
#pragma unroll
  for (int it = 0; it < 4; it++) {
    int r = rr + it * 16;
    ushort4 d = *(const ushort4*)(src + (size_t)(t0 + r) * HD_ + h0 + cc);
    tile[r][cc + 0] = d.x; tile[r][cc + 1] = d.y;
    tile[r][cc + 2] = d.z; tile[r][cc + 3] = d.w;
  }
  __syncthreads();
#pragma unroll
  for (int it = 0; it < 4; it++) {
    int r = rr + it * 16;
    ushort4 d;
    d.x = tile[cc + 0][r]; d.y = tile[cc + 1][r];
    d.z = tile[cc + 2][r]; d.w = tile[cc + 3][r];
    *(ushort4*)(dst + (size_t)(h0 + r) * T_ + t0 + cc) = d;
  }
}

// ---------------- Flash attention (causal, GQA). 128-row Q tile / block, 4 waves.
// LDS 64KB: K tile (reused as P buffer) + Vt tile, both chunked [4][128][32] bf16.
// Q fragments live in registers. Wave w owns Q rows [w*32, w*32+32).
__global__ __launch_bounds__(256, 2) void flash_attn(const unsigned short* __restrict__ q,
                                                     const unsigned short* __restrict__ k,
                                                     const unsigned short* __restrict__ vt,
                                                     unsigned short* __restrict__ y) {
  __shared__ __align__(16) unsigned short KP[4 * 128 * 32];  // K tile, then P
  __shared__ __align__(16) unsigned short Vb[4 * 128 * 32];  // Vt tile
  const int tid = threadIdx.x;
  const int w = tid >> 6, lane = tid & 63;
  const int c = lane & 15, grp = lane >> 4;
  const int lr = lane >> 2, lc = (lane & 3) << 3;
  const int t0 = (15 - (int)blockIdx.x) << 7;   // heavy (late) tiles launch first
  const int h = blockIdx.y, b = blockIdx.z, g = h >> 3;
  const unsigned short* qbase = q + (((size_t)(b * NH_ + h)) * T_ + t0) * HD_;
  const unsigned short* kbase = k + ((size_t)(b * NKV_ + g)) * T_ * HD_;
  const unsigned short* vtbase = vt + ((size_t)(b * NKV_ + g)) * HD_ * T_;

  // Q fragments: qf[ti][ks] = A-frag rows (w*32+ti*16+c), k = ks*32+grp*8..+8
  bf16x8 qf[2][4];
#pragma unroll
  for (int ti = 0; ti < 2; ti++)
#pragma unroll
    for (int ks = 0; ks < 4; ks++)
      qf[ti][ks] = *(const bf16x8*)(qbase + (size_t)(w * 32 + ti * 16 + c) * HD_ + ks * 32 + grp * 8);

  f32x4 oacc[2][8] = {};
  float mrun[8], lrun[8];
#pragma unroll
  for (int i = 0; i < 8; i++) { mrun[i] = -__builtin_inff(); lrun[i] = 0.f; }
  const float scale = 0.08838834764831845f;  // 1/sqrt(128)

  for (int s0 = 0; s0 <= t0; s0 += 128) {
    __syncthreads();  // prior iteration done reading KP/Vb
#pragma unroll
    for (int kc = 0; kc < 4; kc++) {
#pragma unroll
      for (int jj = 0; jj < 2; jj++) {
        int rb = w * 32 + jj * 16;
        load_lds16(kbase + (size_t)(s0 + rb + lr) * HD_ + kc * 32 + lc, &KP[kc * 4096 + rb * 32]);
        load_lds16(vtbase + (size_t)(rb + lr) * T_ + s0 + kc * 32 + lc, &Vb[kc * 4096 + rb * 32]);
      }
    }
    __syncthreads();  // K/V resident

    // S = Q K^T  (strip 32 x 128 per wave)
    f32x4 sacc[2][8] = {};
#pragma unroll
    for (int ks = 0; ks < 4; ks++) {
#pragma unroll
      for (int nj = 0; nj < 8; nj++) {
        bf16x8 bk = *(const bf16x8*)&KP[ks * 4096 + (nj * 16 + c) * 32 + grp * 8];
        sacc[0][nj] = __builtin_amdgcn_mfma_f32_16x16x32_bf16(qf[0][ks], bk, sacc[0][nj], 0, 0, 0);
        sacc[1][nj] = __builtin_amdgcn_mfma_f32_16x16x32_bf16(qf[1][ks], bk, sacc[1][nj], 0, 0, 0);
      }
    }
    const bool diag = (s0 == t0);
#pragma unroll
    for (int ti = 0; ti < 2; ti++)
#pragma unroll
      for (int nj = 0; nj < 8; nj++)
#pragma unroll
        for (int r = 0; r < 4; r++) {
          float sv = sacc[ti][nj][r] * scale;
          if (diag) {
            int trow = w * 32 + ti * 16 + grp * 4 + r;
            int scol = nj * 16 + c;
            if (scol > trow) sv = -__builtin_inff();
          }
          sacc[ti][nj][r] = sv;
        }
    // online softmax (rows replicated over 16 lanes sharing grp)
#pragma unroll
    for (int ti = 0; ti < 2; ti++)
#pragma unroll
      for (int r = 0; r < 4; r++) {
        int si = ti * 4 + r;
        float rm = sacc[ti][0][r];
#pragma unroll
        for (int nj = 1; nj < 8; nj++) rm = fmaxf(rm, sacc[ti][nj][r]);
#pragma unroll
        for (int off = 1; off < 16; off <<= 1) rm = fmaxf(rm, __shfl_xor(rm, off));
        float mnew = fmaxf(mrun[si], rm);
        float alpha = __expf(mrun[si] - mnew);
        mrun[si] = mnew;
        float rs = 0.f;
#pragma unroll
        for (int nj = 0; nj < 8; nj++) {
          float p = __expf(sacc[ti][nj][r] - mnew);
          sacc[ti][nj][r] = p;
          rs += p;
        }
#pragma unroll
        for (int off = 1; off < 16; off <<= 1) rs += __shfl_xor(rs, off);
        lrun[si] = lrun[si] * alpha + rs;
#pragma unroll
        for (int hj = 0; hj < 8; hj++) oacc[ti][hj][r] *= alpha;
      }
    __syncthreads();  // everyone done reading K -> safe to overwrite with P
    // P (bf16) into wave-private region of KP, chunked [ks][32 rows][32 cols]
#pragma unroll
    for (int ti = 0; ti < 2; ti++)
#pragma unroll
      for (int nj = 0; nj < 8; nj++)
#pragma unroll
        for (int r = 0; r < 4; r++) {
          int prow = ti * 16 + grp * 4 + r;
          int pcol = nj * 16 + c;
          KP[w * 4096 + (pcol >> 5) * 1024 + prow * 32 + (pcol & 31)] = f2bf(sacc[ti][nj][r]);
        }
    __syncthreads();  // P visible
    // O += P * V   (A = P strip, B = Vt)
#pragma unroll
    for (int ks = 0; ks < 4; ks++) {
      bf16x8 ap0 = *(const bf16x8*)&KP[w * 4096 + ks * 1024 + c * 32 + grp * 8];
      bf16x8 ap1 = *(const bf16x8*)&KP[w * 4096 + ks * 1024 + (16 + c) * 32 + grp * 8];
#pragma unroll
      for (int hj = 0; hj < 8; hj++) {
        bf16x8 bv = *(const bf16x8*)&Vb[ks * 4096 + (hj * 16 + c) * 32 + grp * 8];
        oacc[0][hj] = __builtin_amdgcn_mfma_f32_16x16x32_bf16(ap0, bv, oacc[0][hj], 0, 0, 0);
        oacc[1][hj] = __builtin_amdgcn_mfma_f32_16x16x32_bf16(ap1, bv, oacc[1][hj], 0, 0, 0);
      }
    }
  }
  // epilogue: O / l -> y (B, T, NH*HD) bf16
#pragma unroll
  for (int ti = 0; ti < 2; ti++)
#pragma unroll
    for (int r = 0; r < 4; r++) {
      int si = ti * 4 + r;
      float inv = 1.f / lrun[si];
      int trow = t0 + w * 32 + ti * 16 + grp * 4 + r;
#pragma unroll
      for (int hj = 0; hj < 8; hj++) {
        int col = h * HD_ + hj * 16 + c;
        y[((size_t)(b * T_ + trow)) * HID_ + col] = f2bf(oacc[ti][hj][r] * inv);
      }
    }
}

// ---------------- launcher ----------------
extern "C" void kernel_launch(void* const* d_in, const int* in_sizes, int n_in,
                              void* d_out, int out_size, void* d_ws, size_t ws_size,
                              hipStream_t stream) {
  const float* x    = (const float*)d_in[0];
  const float* cosb = (const float*)d_in[1];
  const float* sinb = (const float*)d_in[2];
  const float* Wq   = (const float*)d_in[3];
  const float* Wk   = (const float*)d_in[4];
  const float* Wv   = (const float*)d_in[5];
  const float* Wo   = (const float*)d_in[6];
  float* out = (float*)d_out;

  char* ws = (char*)d_ws;
  size_t off = 0;
  auto take = [&](size_t elems) {
    unsigned short* p = (unsigned short*)(ws + off);
    off += ((elems * 2 + 255) & ~(size_t)255);
    return p;
  };
  unsigned short* xb   = take((size_t)M_ * HID_);          // x bf16
  unsigned short* wqkv = take((size_t)NQKV_ * HID_);       // [Wq;Wk;Wv] bf16
  unsigned short* wob  = take((size_t)HID_ * HID_);        // Wo bf16
  unsigned short* qkv  = take((size_t)M_ * NQKV_);         // projections bf16
  unsigned short* qb   = take((size_t)B_ * NH_ * T_ * HD_);  // q (B,NH,T,HD)
  unsigned short* kb   = take((size_t)B_ * NKV_ * T_ * HD_); // k (B,KV,T,HD)
  unsigned short* vb   = take((size_t)B_ * NKV_ * T_ * HD_); // v (B,KV,T,HD)
  unsigned short* vtb  = take((size_t)B_ * NKV_ * T_ * HD_); // v^T (B,KV,HD,T)
  unsigned short* yb   = take((size_t)M_ * HID_);          // attn out bf16
  (void)ws_size; (void)in_sizes; (void)n_in; (void)out_size;

  // casts
  cast_bf16<<<16384, 256, 0, stream>>>(x, xb, 4194304);
  cast_bf16<<<4096, 256, 0, stream>>>(Wq, wqkv, 1048576);
  cast_bf16<<<512, 256, 0, stream>>>(Wk, wqkv + (size_t)2048 * 2048, 131072);
  cast_bf16<<<512, 256, 0, stream>>>(Wv, wqkv + (size_t)2304 * 2048, 131072);
  cast_bf16<<<4096, 256, 0, stream>>>(Wo, wob, 1048576);

  // qkv = x @ Wqkv^T  (M=8192, N=2560, K=2048) -> bf16
  gemm_bt<1><<<dim3(20, 64), 256, 0, stream>>>(xb, wqkv, qkv, M_, NQKV_, HID_);

  // rope + rmsnorm + split
  rope_norm<<<8192, 256, 0, stream>>>(qkv, cosb, sinb, qb, kb, vb);

  // v -> v^T
  transpose_v<<<dim3(32, 2, 8), 256, 0, stream>>>(vb, vtb);

  // causal flash attention -> yb (B,T,2048) bf16
  flash_attn<<<dim3(16, 16, 4), 256, 0, stream>>>(qb, kb, vtb, yb);

  // out = yb @ Wo^T  (M=8192, N=2048, K=2048) -> fp32
  gemm_bt<0><<<dim3(16, 64), 256, 0, stream>>>(yb, wob, out, M_, HID_, HID_);
}

// Round 2
// 553.150 us; speedup vs baseline: 1.1343x; 1.1343x over previous
//
#include <hip/hip_runtime.h>

// Problem constants (B,T,HID)=(4,2048,2048), heads 16, kv 2, hd 128.
#define B_    4
#define T_    2048
#define HID_  2048
#define NH_   16
#define NKV_  2
#define HD_   128
#define M_    (B_ * T_)      // 8192 rows
#define NQKV_ 2560           // 16*128 + 2*128 + 2*128

typedef __bf16 bf16x8 __attribute__((ext_vector_type(8)));
typedef float  f32x4  __attribute__((ext_vector_type(4)));

#define AS1 __attribute__((address_space(1)))
#define AS3 __attribute__((address_space(3)))

#if __has_builtin(__builtin_amdgcn_exp2f)
#define EXP2(x) __builtin_amdgcn_exp2f(x)
#else
#define EXP2(x) exp2f(x)
#endif

// async global->LDS, 16B per lane; LDS dest = wave-uniform base + lane*16
__device__ __forceinline__ void load_lds16(const void* g, void* l) {
  __builtin_amdgcn_global_load_lds((const AS1 unsigned int*)g,
                                   (AS3 unsigned int*)l, 16, 0, 0);
}

__device__ __forceinline__ unsigned short f2bf(float x) {
  union { float f; unsigned u; } a; a.f = x;
  unsigned r = a.u + 0x7fffu + ((a.u >> 16) & 1u);   // RNE
  return (unsigned short)(r >> 16);
}
__device__ __forceinline__ float bf2f(unsigned h) {
  union { unsigned u; float f; } a; a.u = h << 16;
  return a.f;
}
// pack two fp32 -> u32 of two bf16 (RTZ; P in [0,1], bias negligible)
__device__ __forceinline__ unsigned pk_rtz(float lo, float hi) {
  union { float f; unsigned u; } a, b; a.f = lo; b.f = hi;
  return (a.u >> 16) | (b.u & 0xffff0000u);
}

// ---------------- cast f32 -> bf16 (4 elems/thread) ----------------
__global__ __launch_bounds__(256) void cast_bf16(const float* __restrict__ in,
                                                 unsigned short* __restrict__ out,
                                                 int n4) {
  int i = blockIdx.x * 256 + threadIdx.x;
  if (i >= n4) return;
  float4 v = ((const float4*)in)[i];
  ushort4 o;
  o.x = f2bf(v.x); o.y = f2bf(v.y); o.z = f2bf(v.z); o.w = f2bf(v.w);
  ((ushort4*)out)[i] = o;
}

// ---------------- GEMM C = A * B^T (A: MxK row-major bf16, B: NxK row-major bf16)
template <int OUT_BF16>
__global__ __launch_bounds__(256) void gemm_bt(const unsigned short* __restrict__ A,
                                               const unsigned short* __restrict__ Bm,
                                               void* __restrict__ C,
                                               int M, int N, int K) {
  __shared__ __align__(16) unsigned short As[128 * 32];
  __shared__ __align__(16) unsigned short Bs[128 * 32];
  const int tid = threadIdx.x;
  const int w = tid >> 6, lane = tid & 63;
  const int m0 = blockIdx.y << 7, n0 = blockIdx.x << 7;
  const int c = lane & 15, grp = lane >> 4;
  const int lr = lane >> 2, lc = (lane & 3) << 3;
  const int wm = (w & 1) << 6, wn = (w >> 1) << 6;
  f32x4 acc[4][4] = {};
  for (int k0 = 0; k0 < K; k0 += 32) {
    __syncthreads();
    {
      int r0 = w << 4;
      load_lds16(A + (size_t)(m0 + r0 + lr) * K + k0 + lc, &As[r0 * 32]);
      load_lds16(A + (size_t)(m0 + 64 + r0 + lr) * K + k0 + lc, &As[(64 + r0) * 32]);
      load_lds16(Bm + (size_t)(n0 + r0 + lr) * K + k0 + lc, &Bs[r0 * 32]);
      load_lds16(Bm + (size_t)(n0 + 64 + r0 + lr) * K + k0 + lc, &Bs[(64 + r0) * 32]);
    }
    __syncthreads();
    bf16x8 af[4], bf[4];
#pragma unroll
    for (int i = 0; i < 4; i++)
      af[i] = *(const bf16x8*)&As[(wm + i * 16 + c) * 32 + grp * 8];
#pragma unroll
    for (int j = 0; j < 4; j++)
      bf[j] = *(const bf16x8*)&Bs[(wn + j * 16 + c) * 32 + grp * 8];
#pragma unroll
    for (int i = 0; i < 4; i++)
#pragma unroll
      for (int j = 0; j < 4; j++)
        acc[i][j] = __builtin_amdgcn_mfma_f32_16x16x32_bf16(af[i], bf[j], acc[i][j], 0, 0, 0);
  }
#pragma unroll
  for (int i = 0; i < 4; i++)
#pragma unroll
    for (int j = 0; j < 4; j++)
#pragma unroll
      for (int r = 0; r < 4; r++) {
        int row = m0 + wm + i * 16 + grp * 4 + r;
        int col = n0 + wn + j * 16 + c;
        float v = acc[i][j][r];
        if (OUT_BF16) ((unsigned short*)C)[(size_t)row * N + col] = f2bf(v);
        else          ((float*)C)[(size_t)row * N + col] = v;
      }
}

// ---------------- RoPE + RMSNorm. One wave per head per (b,t).
// q additionally pre-scaled by attn_scale*log2(e) so flash's softmax uses exp2 directly.
__global__ __launch_bounds__(256) void rope_norm(const unsigned short* __restrict__ qkv,
                                                 const float* __restrict__ cosb,
                                                 const float* __restrict__ sinb,
                                                 unsigned short* __restrict__ qo,
                                                 unsigned short* __restrict__ ko,
                                                 unsigned short* __restrict__ vo) {
  const int m = blockIdx.x;
  const int b = m >> 11, t = m & 2047;
  const int w = threadIdx.x >> 6, lane = threadIdx.x & 63;
  const float cv = cosb[t * 64 + lane], sv = sinb[t * 64 + lane];
  const unsigned short* row = qkv + (size_t)m * NQKV_;
  const float QSCL = 0.08838834764831845f * 1.4426950408889634f;  // 1/sqrt(128)*log2(e)
  for (int hh = w; hh < 20; hh += 4) {
    if (hh < 18) {
      const int col0 = (hh < 16) ? hh * 128 : 2048 + (hh - 16) * 128;
      unsigned pr = *(const unsigned*)(row + col0 + 2 * lane);
      float xr = bf2f(pr & 0xffffu), xi = bf2f(pr >> 16);
      float orr = xr * cv - xi * sv;
      float oi  = xr * sv + xi * cv;
      float ss = orr * orr + oi * oi;
#pragma unroll
      for (int off = 1; off < 64; off <<= 1) ss += __shfl_xor(ss, off);
      float scl = rsqrtf(ss * (1.0f / 128.0f) + 1.1920929e-07f);  // fp32 eps
      if (hh < 16) {
        float s2 = scl * QSCL;
        unsigned out = (unsigned)f2bf(orr * s2) | ((unsigned)f2bf(oi * s2) << 16);
        *(unsigned*)(qo + (((size_t)(b * NH_ + hh)) * T_ + t) * HD_ + 2 * lane) = out;
      } else {
        unsigned out = (unsigned)f2bf(orr * scl) | ((unsigned)f2bf(oi * scl) << 16);
        *(unsigned*)(ko + (((size_t)(b * NKV_ + (hh - 16))) * T_ + t) * HD_ + 2 * lane) = out;
      }
    } else {
      const int gg = hh - 18;
      unsigned pr = *(const unsigned*)(row + 2304 + gg * 128 + 2 * lane);
      *(unsigned*)(vo + (((size_t)(b * NKV_ + gg)) * T_ + t) * HD_ + 2 * lane) = pr;
    }
  }
}

// ---------------- V transpose: (bg, T, HD) -> (bg, HD, T), 64x64 LDS tiles
__global__ __launch_bounds__(256) void transpose_v(const unsigned short* __restrict__ v,
                                                   unsigned short* __restrict__ vt) {
  __shared__ unsigned short tile[64][65];
  const int bg = blockIdx.z;
  const int t0 = blockIdx.x << 6, h0 = blockIdx.y << 6;
  const unsigned short* src = v + (size_t)bg * T_ * HD_;
  unsigned short* dst = vt + (size_t)bg * T_ * HD_;
  const int tid = threadIdx.x;
  const int rr = tid >> 4, cc = (tid & 15) << 2;
#pragma unroll
  for (int it = 0; it < 4; it++) {
    int r = rr + it * 16;
    ushort4 d = *(const ushort4*)(src + (size_t)(t0 + r) * HD_ + h0 + cc);
    tile[r][cc + 0] = d.x; tile[r][cc + 1] = d.y;
    tile[r][cc + 2] = d.z; tile[r][cc + 3] = d.w;
  }
  __syncthreads();
#pragma unroll
  for (int it = 0; it < 4; it++) {
    int r = rr + it * 16;
    ushort4 d;
    d.x = tile[cc + 0][r]; d.y = tile[cc + 1][r];
    d.z = tile[cc + 2][r]; d.w = tile[cc + 3][r];
    *(ushort4*)(dst + (size_t)(h0 + r) * T_ + t0 + cc) = d;
  }
}

// ---------------- Flash attention v2 (S^T form, no P LDS round-trip).
// Per 128-q block, 4 waves (32 q each). S^T = K·Q^T so each lane owns q=c columns;
// PV uses a permuted k-order (pi(k)=32ks+((k&4)?16:0)+(k>>3)*4+(k&3)) making the
// P fragment fully lane-local. V LDS is XOR-swizzled on 8B units by (row&6) to
// keep the two b64 fragment reads ~conflict-free. One barrier pair per KV tile.
__global__ __launch_bounds__(256, 2) void flash_attn(const unsigned short* __restrict__ q,
                                                     const unsigned short* __restrict__ k,
                                                     const unsigned short* __restrict__ vt,
                                                     unsigned short* __restrict__ y) {
  __shared__ __align__(16) unsigned short Kb[4 * 128 * 32];  // [kc d-chunk][kv 128][d 32]
  __shared__ __align__(16) unsigned short Vb[4 * 128 * 32];  // [ks kv-chunk][h 128][kv 32] swizzled
  const int tid = threadIdx.x;
  const int w = tid >> 6, lane = tid & 63;
  const int c = lane & 15, grp = lane >> 4;
  const int lr = lane >> 2, lc = (lane & 3) << 3;
  const int t0 = (15 - (int)blockIdx.x) << 7;   // heavy (late) tiles launch first
  const int hq = blockIdx.y, b = blockIdx.z, g = hq >> 3;
  const unsigned short* qbase = q + (((size_t)(b * NH_ + hq)) * T_ + t0) * HD_;
  const unsigned short* kbase = k + ((size_t)(b * NKV_ + g)) * T_ * HD_;
  const unsigned short* vtbase = vt + ((size_t)(b * NKV_ + g)) * HD_ * T_;

  // Q fragments (pre-scaled by scale*log2e in rope_norm): rows q, B-operand layout
  bf16x8 qf[2][4];
#pragma unroll
  for (int ti = 0; ti < 2; ti++)
#pragma unroll
    for (int ks = 0; ks < 4; ks++)
      qf[ti][ks] = *(const bf16x8*)(qbase + (size_t)(w * 32 + ti * 16 + c) * HD_ + ks * 32 + grp * 8);

  f32x4 oacc[2][8] = {};                 // O^T: row h=grp*4+r (hj tiles), col q=ti*16+c
  float mrun[2], lrun[2];
  mrun[0] = mrun[1] = -__builtin_inff();
  lrun[0] = lrun[1] = 0.f;

  const int swl = (((lane & 3) << 1) ^ (lr & 6)) << 2;  // staging: logical unit -> ushort off
  const int sw = c & 6;                                 // read-side swizzle

  for (int s0 = 0; s0 <= t0; s0 += 128) {
    __syncthreads();  // prior iteration done reading Kb/Vb
#pragma unroll
    for (int kc = 0; kc < 4; kc++) {
#pragma unroll
      for (int jj = 0; jj < 2; jj++) {
        int rb = w * 32 + jj * 16;
        load_lds16(kbase + (size_t)(s0 + rb + lr) * HD_ + kc * 32 + lc, &Kb[kc * 4096 + rb * 32]);
        load_lds16(vtbase + (size_t)(rb + lr) * T_ + s0 + kc * 32 + swl, &Vb[kc * 4096 + rb * 32]);
      }
    }
    __syncthreads();  // K/V resident

    // S^T = K·Q^T : A=K rows (m=kv), B=Q rows (n=q). st[ti][kvt]: lane holds
    // P[q=ti*16+c][kv = kvt*16 + grp*4 + r]  (log2-domain, pre-scaled).
    f32x4 st[2][8] = {};
#pragma unroll
    for (int ks = 0; ks < 4; ks++) {
#pragma unroll
      for (int kvt = 0; kvt < 8; kvt++) {
        bf16x8 ak = *(const bf16x8*)&Kb[ks * 4096 + (kvt * 16 + c) * 32 + grp * 8];
        st[0][kvt] = __builtin_amdgcn_mfma_f32_16x16x32_bf16(ak, qf[0][ks], st[0][kvt], 0, 0, 0);
        st[1][kvt] = __builtin_amdgcn_mfma_f32_16x16x32_bf16(ak, qf[1][ks], st[1][kvt], 0, 0, 0);
      }
    }
    if (s0 == t0) {  // causal mask on the diagonal tile
#pragma unroll
      for (int ti = 0; ti < 2; ti++)
#pragma unroll
        for (int kvt = 0; kvt < 8; kvt++)
#pragma unroll
          for (int r = 0; r < 4; r++) {
            int kv = kvt * 16 + grp * 4 + r;
            int qq = w * 32 + ti * 16 + c;
            if (kv > qq) st[ti][kvt][r] = -__builtin_inff();
          }
    }

    // online softmax per q-column (lane-local + cross-grp butterfly)
    unsigned pkv[2][8][2];
#pragma unroll
    for (int ti = 0; ti < 2; ti++) {
      float rm = st[ti][0][0];
#pragma unroll
      for (int kvt = 0; kvt < 8; kvt++)
#pragma unroll
        for (int r = 0; r < 4; r++) rm = fmaxf(rm, st[ti][kvt][r]);
      rm = fmaxf(rm, __shfl_xor(rm, 16));
      rm = fmaxf(rm, __shfl_xor(rm, 32));
      float mnew = fmaxf(mrun[ti], rm);
      float alpha = EXP2(mrun[ti] - mnew);
      mrun[ti] = mnew;
      float rs = 0.f;
#pragma unroll
      for (int kvt = 0; kvt < 8; kvt++) {
        float p0 = EXP2(st[ti][kvt][0] - mnew);
        float p1 = EXP2(st[ti][kvt][1] - mnew);
        float p2 = EXP2(st[ti][kvt][2] - mnew);
        float p3 = EXP2(st[ti][kvt][3] - mnew);
        rs += (p0 + p1) + (p2 + p3);
        pkv[ti][kvt][0] = pk_rtz(p0, p1);
        pkv[ti][kvt][1] = pk_rtz(p2, p3);
      }
      rs += __shfl_xor(rs, 16);
      rs += __shfl_xor(rs, 32);
      lrun[ti] = lrun[ti] * alpha + rs;
#pragma unroll
      for (int hj = 0; hj < 8; hj++)
#pragma unroll
        for (int r = 0; r < 4; r++) oacc[ti][hj][r] *= alpha;
    }

    // O^T += V^T·P : A = Vt rows (m=h), B = P (n=q), k permuted by pi.
#pragma unroll
    for (int ks = 0; ks < 4; ks++) {
      union { int4 i; bf16x8 v; } pf0, pf1;
      pf0.i = make_int4(pkv[0][2 * ks][0], pkv[0][2 * ks][1], pkv[0][2 * ks + 1][0], pkv[0][2 * ks + 1][1]);
      pf1.i = make_int4(pkv[1][2 * ks][0], pkv[1][2 * ks][1], pkv[1][2 * ks + 1][0], pkv[1][2 * ks + 1][1]);
#pragma unroll
      for (int hj = 0; hj < 8; hj++) {
        const unsigned short* vrow = &Vb[ks * 4096 + (hj * 16 + c) * 32];
        int u0 = (grp ^ sw) << 2;
        uint2 v0 = *(const uint2*)(vrow + u0);
        uint2 v1 = *(const uint2*)(vrow + (u0 ^ 16));
        union { int4 i; bf16x8 v; } av;
        av.i = make_int4((int)v0.x, (int)v0.y, (int)v1.x, (int)v1.y);
        oacc[0][hj] = __builtin_amdgcn_mfma_f32_16x16x32_bf16(av.v, pf0.v, oacc[0][hj], 0, 0, 0);
        oacc[1][hj] = __builtin_amdgcn_mfma_f32_16x16x32_bf16(av.v, pf1.v, oacc[1][hj], 0, 0, 0);
      }
    }
  }

  // epilogue: lane owns O^T[h=hj*16+grp*4+r][q=ti*16+c]; l is lane-local.
#pragma unroll
  for (int ti = 0; ti < 2; ti++) {
    float inv = 1.f / lrun[ti];
    int trow = t0 + w * 32 + ti * 16 + c;
#pragma unroll
    for (int hj = 0; hj < 8; hj++) {
      ushort4 o;
      o.x = f2bf(oacc[ti][hj][0] * inv);
      o.y = f2bf(oacc[ti][hj][1] * inv);
      o.z = f2bf(oacc[ti][hj][2] * inv);
      o.w = f2bf(oacc[ti][hj][3] * inv);
      *(ushort4*)&y[((size_t)(b * T_ + trow)) * HID_ + hq * HD_ + hj * 16 + grp * 4] = o;
    }
  }
}

// ---------------- launcher ----------------
extern "C" void kernel_launch(void* const* d_in, const int* in_sizes, int n_in,
                              void* d_out, int out_size, void* d_ws, size_t ws_size,
                              hipStream_t stream) {
  const float* x    = (const float*)d_in[0];
  const float* cosb = (const float*)d_in[1];
  const float* sinb = (const float*)d_in[2];
  const float* Wq   = (const float*)d_in[3];
  const float* Wk   = (const float*)d_in[4];
  const float* Wv   = (const float*)d_in[5];
  const float* Wo   = (const float*)d_in[6];
  float* out = (float*)d_out;

  char* ws = (char*)d_ws;
  size_t off = 0;
  auto take = [&](size_t elems) {
    unsigned short* p = (unsigned short*)(ws + off);
    off += ((elems * 2 + 255) & ~(size_t)255);
    return p;
  };
  unsigned short* xb   = take((size_t)M_ * HID_);
  unsigned short* wqkv = take((size_t)NQKV_ * HID_);
  unsigned short* wob  = take((size_t)HID_ * HID_);
  unsigned short* qkv  = take((size_t)M_ * NQKV_);
  unsigned short* qb   = take((size_t)B_ * NH_ * T_ * HD_);
  unsigned short* kb   = take((size_t)B_ * NKV_ * T_ * HD_);
  unsigned short* vb   = take((size_t)B_ * NKV_ * T_ * HD_);
  unsigned short* vtb  = take((size_t)B_ * NKV_ * T_ * HD_);
  unsigned short* yb   = take((size_t)M_ * HID_);
  (void)ws_size; (void)in_sizes; (void)n_in; (void)out_size;

  cast_bf16<<<16384, 256, 0, stream>>>(x, xb, 4194304);
  cast_bf16<<<4096, 256, 0, stream>>>(Wq, wqkv, 1048576);
  cast_bf16<<<512, 256, 0, stream>>>(Wk, wqkv + (size_t)2048 * 2048, 131072);
  cast_bf16<<<512, 256, 0, stream>>>(Wv, wqkv + (size_t)2304 * 2048, 131072);
  cast_bf16<<<4096, 256, 0, stream>>>(Wo, wob, 1048576);

  gemm_bt<1><<<dim3(20, 64), 256, 0, stream>>>(xb, wqkv, qkv, M_, NQKV_, HID_);
  rope_norm<<<8192, 256, 0, stream>>>(qkv, cosb, sinb, qb, kb, vb);
  transpose_v<<<dim3(32, 2, 8), 256, 0, stream>>>(vb, vtb);
  flash_attn<<<dim3(16, 16, 4), 256, 0, stream>>>(qb, kb, vtb, yb);
  gemm_bt<0><<<dim3(16, 64), 256, 0, stream>>>(yb, wob, out, M_, HID_, HID_);
}

// Round 3
// 549.776 us; speedup vs baseline: 1.1412x; 1.0061x over previous
//
#include <hip/hip_runtime.h>

// Problem constants (B,T,HID)=(4,2048,2048), heads 16, kv 2, hd 128.
#define B_    4
#define T_    2048
#define HID_  2048
#define NH_   16
#define NKV_  2
#define HD_   128
#define M_    (B_ * T_)      // 8192 rows
#define NQKV_ 2560           // 16*128 + 2*128 + 2*128

typedef __bf16 bf16x8 __attribute__((ext_vector_type(8)));
typedef float  f32x4  __attribute__((ext_vector_type(4)));

#define AS1 __attribute__((address_space(1)))
#define AS3 __attribute__((address_space(3)))

#if __has_builtin(__builtin_amdgcn_exp2f)
#define EXP2(x) __builtin_amdgcn_exp2f(x)
#else
#define EXP2(x) exp2f(x)
#endif

// async global->LDS, 16B per lane; LDS dest = wave-uniform base + lane*16
__device__ __forceinline__ void load_lds16(const void* g, void* l) {
  __builtin_amdgcn_global_load_lds((const AS1 unsigned int*)g,
                                   (AS3 unsigned int*)l, 16, 0, 0);
}

__device__ __forceinline__ unsigned short f2bf(float x) {
  union { float f; unsigned u; } a; a.f = x;
  unsigned r = a.u + 0x7fffu + ((a.u >> 16) & 1u);   // RNE
  return (unsigned short)(r >> 16);
}
__device__ __forceinline__ float bf2f(unsigned h) {
  union { unsigned u; float f; } a; a.u = h << 16;
  return a.f;
}
// pack two fp32 -> u32 of two bf16 (RTZ; P in [0,1], bias negligible)
__device__ __forceinline__ unsigned pk_rtz(float lo, float hi) {
  union { float f; unsigned u; } a, b; a.f = lo; b.f = hi;
  return (a.u >> 16) | (b.u & 0xffff0000u);
}

// ---------------- cast f32 -> bf16 (4 elems/thread) ----------------
__global__ __launch_bounds__(256) void cast_bf16(const float* __restrict__ in,
                                                 unsigned short* __restrict__ out,
                                                 int n4) {
  int i = blockIdx.x * 256 + threadIdx.x;
  if (i >= n4) return;
  float4 v = ((const float4*)in)[i];
  ushort4 o;
  o.x = f2bf(v.x); o.y = f2bf(v.y); o.z = f2bf(v.z); o.w = f2bf(v.w);
  ((ushort4*)out)[i] = o;
}

// merged Wq|Wk|Wv cast into contiguous wqkv (dest float4-index == i)
__global__ __launch_bounds__(256) void cast_w(const float* __restrict__ Wq,
                                              const float* __restrict__ Wk,
                                              const float* __restrict__ Wv,
                                              unsigned short* __restrict__ out) {
  int i = blockIdx.x * 256 + threadIdx.x;  // 5120*256 = 1310720 exact
  const float* src; int j;
  if (i < 1048576)      { src = Wq; j = i; }
  else if (i < 1179648) { src = Wk; j = i - 1048576; }
  else                  { src = Wv; j = i - 1179648; }
  float4 v = ((const float4*)src)[j];
  ushort4 o;
  o.x = f2bf(v.x); o.y = f2bf(v.y); o.z = f2bf(v.z); o.w = f2bf(v.w);
  ((ushort4*)out)[i] = o;
}

// ---------------- GEMM C = A * B^T (A: MxK row-major bf16, B: NxK row-major bf16)
// m97-style + 16B-unit XOR swizzle by (row>>1)&3 to kill fragment-read bank conflicts.
template <int OUT_BF16>
__global__ __launch_bounds__(256) void gemm_bt(const unsigned short* __restrict__ A,
                                               const unsigned short* __restrict__ Bm,
                                               void* __restrict__ C,
                                               int M, int N, int K) {
  __shared__ __align__(16) unsigned short As[128 * 32];
  __shared__ __align__(16) unsigned short Bs[128 * 32];
  const int tid = threadIdx.x;
  const int w = tid >> 6, lane = tid & 63;
  const int m0 = blockIdx.y << 7, n0 = blockIdx.x << 7;
  const int c = lane & 15, grp = lane >> 4;
  const int lr = lane >> 2;
  const int su = (((lane & 3) ^ ((lr >> 1) & 3)) << 3);   // staging source unit (swizzled)
  const int sw = (c >> 1) & 3;                            // read-side swizzle key
  const int wm = (w & 1) << 6, wn = (w >> 1) << 6;
  f32x4 acc[4][4] = {};
  for (int k0 = 0; k0 < K; k0 += 32) {
    __syncthreads();
    {
      int r0 = w << 4;
      load_lds16(A + (size_t)(m0 + r0 + lr) * K + k0 + su, &As[r0 * 32]);
      load_lds16(A + (size_t)(m0 + 64 + r0 + lr) * K + k0 + su, &As[(64 + r0) * 32]);
      load_lds16(Bm + (size_t)(n0 + r0 + lr) * K + k0 + su, &Bs[r0 * 32]);
      load_lds16(Bm + (size_t)(n0 + 64 + r0 + lr) * K + k0 + su, &Bs[(64 + r0) * 32]);
    }
    __syncthreads();
    bf16x8 af[4], bf[4];
#pragma unroll
    for (int i = 0; i < 4; i++)
      af[i] = *(const bf16x8*)&As[(wm + i * 16 + c) * 32 + ((grp ^ sw) << 3)];
#pragma unroll
    for (int j = 0; j < 4; j++)
      bf[j] = *(const bf16x8*)&Bs[(wn + j * 16 + c) * 32 + ((grp ^ sw) << 3)];
#pragma unroll
    for (int i = 0; i < 4; i++)
#pragma unroll
      for (int j = 0; j < 4; j++)
        acc[i][j] = __builtin_amdgcn_mfma_f32_16x16x32_bf16(af[i], bf[j], acc[i][j], 0, 0, 0);
  }
#pragma unroll
  for (int i = 0; i < 4; i++)
#pragma unroll
    for (int j = 0; j < 4; j++)
#pragma unroll
      for (int r = 0; r < 4; r++) {
        int row = m0 + wm + i * 16 + grp * 4 + r;
        int col = n0 + wn + j * 16 + c;
        float v = acc[i][j][r];
        if (OUT_BF16) ((unsigned short*)C)[(size_t)row * N + col] = f2bf(v);
        else          ((float*)C)[(size_t)row * N + col] = v;
      }
}

// ---------------- RoPE + RMSNorm. One wave per head per (b,t).
// q additionally pre-scaled by attn_scale*log2(e) so flash's softmax uses exp2 directly.
__global__ __launch_bounds__(256) void rope_norm(const unsigned short* __restrict__ qkv,
                                                 const float* __restrict__ cosb,
                                                 const float* __restrict__ sinb,
                                                 unsigned short* __restrict__ qo,
                                                 unsigned short* __restrict__ ko,
                                                 unsigned short* __restrict__ vo) {
  const int m = blockIdx.x;
  const int b = m >> 11, t = m & 2047;
  const int w = threadIdx.x >> 6, lane = threadIdx.x & 63;
  const float cv = cosb[t * 64 + lane], sv = sinb[t * 64 + lane];
  const unsigned short* row = qkv + (size_t)m * NQKV_;
  const float QSCL = 0.08838834764831845f * 1.4426950408889634f;  // 1/sqrt(128)*log2(e)
  for (int hh = w; hh < 20; hh += 4) {
    if (hh < 18) {
      const int col0 = (hh < 16) ? hh * 128 : 2048 + (hh - 16) * 128;
      unsigned pr = *(const unsigned*)(row + col0 + 2 * lane);
      float xr = bf2f(pr & 0xffffu), xi = bf2f(pr >> 16);
      float orr = xr * cv - xi * sv;
      float oi  = xr * sv + xi * cv;
      float ss = orr * orr + oi * oi;
#pragma unroll
      for (int off = 1; off < 64; off <<= 1) ss += __shfl_xor(ss, off);
      float scl = rsqrtf(ss * (1.0f / 128.0f) + 1.1920929e-07f);  // fp32 eps
      if (hh < 16) {
        float s2 = scl * QSCL;
        unsigned out = (unsigned)f2bf(orr * s2) | ((unsigned)f2bf(oi * s2) << 16);
        *(unsigned*)(qo + (((size_t)(b * NH_ + hh)) * T_ + t) * HD_ + 2 * lane) = out;
      } else {
        unsigned out = (unsigned)f2bf(orr * scl) | ((unsigned)f2bf(oi * scl) << 16);
        *(unsigned*)(ko + (((size_t)(b * NKV_ + (hh - 16))) * T_ + t) * HD_ + 2 * lane) = out;
      }
    } else {
      const int gg = hh - 18;
      unsigned pr = *(const unsigned*)(row + 2304 + gg * 128 + 2 * lane);
      *(unsigned*)(vo + (((size_t)(b * NKV_ + gg)) * T_ + t) * HD_ + 2 * lane) = pr;
    }
  }
}

// ---------------- V transpose: (bg, T, HD) -> (bg, HD, T), 64x64 LDS tiles.
// Output columns are PERMUTED within each 32-kv chunk so flash's PV A-fragment
// is one contiguous b128: position p=8g+4a+b holds kv=16a+4g+b.
__global__ __launch_bounds__(256) void transpose_v(const unsigned short* __restrict__ v,
                                                   unsigned short* __restrict__ vt) {
  __shared__ unsigned short tile[64][65];
  const int bg = blockIdx.z;
  const int t0 = blockIdx.x << 6, h0 = blockIdx.y << 6;
  const unsigned short* src = v + (size_t)bg * T_ * HD_;
  unsigned short* dst = vt + (size_t)bg * T_ * HD_;
  const int tid = threadIdx.x;
  const int rr = tid >> 4, cc = (tid & 15) << 2;
  const int u = (cc >> 2) & 7;
  const int cp = (cc & 32) + 16 * (u & 1) + 4 * ((u >> 1) & 3);  // source col for dst col cc
#pragma unroll
  for (int it = 0; it < 4; it++) {
    int r = rr + it * 16;
    ushort4 d = *(const ushort4*)(src + (size_t)(t0 + r) * HD_ + h0 + cc);
    tile[r][cc + 0] = d.x; tile[r][cc + 1] = d.y;
    tile[r][cc + 2] = d.z; tile[r][cc + 3] = d.w;
  }
  __syncthreads();
#pragma unroll
  for (int it = 0; it < 4; it++) {
    int r = rr + it * 16;
    ushort4 d;
    d.x = tile[cp + 0][r]; d.y = tile[cp + 1][r];
    d.z = tile[cp + 2][r]; d.w = tile[cp + 3][r];
    *(ushort4*)(dst + (size_t)(h0 + r) * T_ + t0 + cc) = d;
  }
}

// ---------------- Flash attention v3: S^T form, lane-local P, double-buffered
// 64-kv chunks (one barrier per chunk, loads issued a full compute-phase before
// their drain), XOR-swizzled K/V LDS, b128-only fragment reads.
__global__ __launch_bounds__(256, 2) void flash_attn(const unsigned short* __restrict__ q,
                                                     const unsigned short* __restrict__ k,
                                                     const unsigned short* __restrict__ vt,
                                                     unsigned short* __restrict__ y) {
  __shared__ __align__(16) unsigned short Kb[2][8192];  // [buf][dc4][kv64][d-unit swz]
  __shared__ __align__(16) unsigned short Vb[2][8192];  // [buf][ks2][h128][kv-unit swz]
  const int tid = threadIdx.x;
  const int w = tid >> 6, lane = tid & 63;
  const int c = lane & 15, grp = lane >> 4;
  const int lr = lane >> 2;
  const int sw = (c >> 1) & 3;
  const int su = (((lane & 3) ^ ((lr >> 1) & 3)) << 3);
  const int t0 = (15 - (int)blockIdx.x) << 7;   // heavy (late) tiles launch first
  const int t0w = t0 + w * 32;
  const int hq = blockIdx.y, b = blockIdx.z, g = hq >> 3;
  const unsigned short* qbase = q + (((size_t)(b * NH_ + hq)) * T_ + t0) * HD_;
  const unsigned short* kbase = k + ((size_t)(b * NKV_ + g)) * T_ * HD_;
  const unsigned short* vtbase = vt + ((size_t)(b * NKV_ + g)) * HD_ * T_;

  // Q fragments (pre-scaled by scale*log2e): B-operand layout, rows q
  bf16x8 qf[2][4];
#pragma unroll
  for (int ti = 0; ti < 2; ti++)
#pragma unroll
    for (int ks = 0; ks < 4; ks++)
      qf[ti][ks] = *(const bf16x8*)(qbase + (size_t)(w * 32 + ti * 16 + c) * HD_ + ks * 32 + grp * 8);

  f32x4 oacc[2][8] = {};            // O^T: row h=hj*16+grp*4+r, col q=ti*16+c
  float mrun[2], lrun[2];
  mrun[0] = mrun[1] = -__builtin_inff();
  lrun[0] = lrun[1] = 0.f;

  auto stage = [&](int s0, int bb) {
    const unsigned short* kp = kbase + (size_t)(s0 + w * 16 + lr) * HD_ + su;
#pragma unroll
    for (int dc = 0; dc < 4; dc++)
      load_lds16(kp + dc * 32, &Kb[bb][dc * 2048 + (w * 16) * 32]);
    const unsigned short* vp = vtbase + s0 + su;
#pragma unroll
    for (int ks = 0; ks < 2; ks++)
#pragma unroll
      for (int jj = 0; jj < 2; jj++)
        load_lds16(vp + (size_t)(w * 32 + jj * 16 + lr) * T_ + ks * 32,
                   &Vb[bb][ks * 4096 + (w * 32 + jj * 16) * 32]);
  };

  const int nch = (t0 >> 6) + 2;
  stage(0, 0);
  __syncthreads();                       // chunk 0 resident
  for (int ic = 0; ic < nch; ic++) {
    const int s0 = ic << 6, bb = ic & 1;
    if (ic + 1 < nch) stage((ic + 1) << 6, bb ^ 1);   // async prefetch, drained at loop-end barrier
    if (s0 <= t0w + 31) {                // wave has unmasked work in this chunk
      const unsigned short* Kc = Kb[bb];
      const unsigned short* Vc = Vb[bb];
      // S^T = K·Q^T : lane holds P[q=ti*16+c][kv=kvt*16+grp*4+r] (log2 domain)
      f32x4 st[2][4] = {};
#pragma unroll
      for (int s = 0; s < 4; s++)
#pragma unroll
        for (int kvt = 0; kvt < 4; kvt++) {
          bf16x8 ak = *(const bf16x8*)&Kc[s * 2048 + (kvt * 16 + c) * 32 + ((grp ^ sw) << 3)];
          st[0][kvt] = __builtin_amdgcn_mfma_f32_16x16x32_bf16(ak, qf[0][s], st[0][kvt], 0, 0, 0);
          st[1][kvt] = __builtin_amdgcn_mfma_f32_16x16x32_bf16(ak, qf[1][s], st[1][kvt], 0, 0, 0);
        }
      if (s0 + 63 > t0w) {               // diagonal chunk: causal mask
#pragma unroll
        for (int ti = 0; ti < 2; ti++)
#pragma unroll
          for (int kvt = 0; kvt < 4; kvt++)
#pragma unroll
            for (int r = 0; r < 4; r++) {
              int kv = s0 + kvt * 16 + grp * 4 + r;
              int qq = t0w + ti * 16 + c;
              if (kv > qq) st[ti][kvt][r] = -__builtin_inff();
            }
      }
      // online softmax per q-column (lane-local + cross-grp butterfly)
      unsigned pkv[2][4][2];
#pragma unroll
      for (int ti = 0; ti < 2; ti++) {
        float rm = st[ti][0][0];
#pragma unroll
        for (int kvt = 0; kvt < 4; kvt++)
#pragma unroll
          for (int r = 0; r < 4; r++) rm = fmaxf(rm, st[ti][kvt][r]);
        rm = fmaxf(rm, __shfl_xor(rm, 16));
        rm = fmaxf(rm, __shfl_xor(rm, 32));
        float mnew = fmaxf(mrun[ti], rm);
        float alpha = EXP2(mrun[ti] - mnew);
        mrun[ti] = mnew;
        float rs = 0.f;
#pragma unroll
        for (int kvt = 0; kvt < 4; kvt++) {
          float p0 = EXP2(st[ti][kvt][0] - mnew);
          float p1 = EXP2(st[ti][kvt][1] - mnew);
          float p2 = EXP2(st[ti][kvt][2] - mnew);
          float p3 = EXP2(st[ti][kvt][3] - mnew);
          rs += (p0 + p1) + (p2 + p3);
          pkv[ti][kvt][0] = pk_rtz(p0, p1);
          pkv[ti][kvt][1] = pk_rtz(p2, p3);
        }
        rs += __shfl_xor(rs, 16);
        rs += __shfl_xor(rs, 32);
        lrun[ti] = lrun[ti] * alpha + rs;
#pragma unroll
        for (int hj = 0; hj < 8; hj++)
#pragma unroll
          for (int r = 0; r < 4; r++) oacc[ti][hj][r] *= alpha;
      }
      // O^T += V^T·P (k permuted; V pre-permuted so A-frag is one b128)
#pragma unroll
      for (int s = 0; s < 2; s++) {
        union { int4 i; bf16x8 v; } pf0, pf1;
        pf0.i = make_int4(pkv[0][2 * s][0], pkv[0][2 * s][1], pkv[0][2 * s + 1][0], pkv[0][2 * s + 1][1]);
        pf1.i = make_int4(pkv[1][2 * s][0], pkv[1][2 * s][1], pkv[1][2 * s + 1][0], pkv[1][2 * s + 1][1]);
#pragma unroll
        for (int hj = 0; hj < 8; hj++) {
          union { int4 i; bf16x8 v; } av;
          av.i = *(const int4*)&Vc[s * 4096 + (hj * 16 + c) * 32 + ((grp ^ sw) << 3)];
          oacc[0][hj] = __builtin_amdgcn_mfma_f32_16x16x32_bf16(av.v, pf0.v, oacc[0][hj], 0, 0, 0);
          oacc[1][hj] = __builtin_amdgcn_mfma_f32_16x16x32_bf16(av.v, pf1.v, oacc[1][hj], 0, 0, 0);
        }
      }
    }
    __syncthreads();   // drains prefetch (issued a full compute ago) + buffer handoff
  }

  // epilogue: lane owns O^T[h][q=ti*16+c]; l is lane-local.
#pragma unroll
  for (int ti = 0; ti < 2; ti++) {
    float inv = 1.f / lrun[ti];
    int trow = t0 + w * 32 + ti * 16 + c;
#pragma unroll
    for (int hj = 0; hj < 8; hj++) {
      ushort4 o;
      o.x = f2bf(oacc[ti][hj][0] * inv);
      o.y = f2bf(oacc[ti][hj][1] * inv);
      o.z = f2bf(oacc[ti][hj][2] * inv);
      o.w = f2bf(oacc[ti][hj][3] * inv);
      *(ushort4*)&y[((size_t)(b * T_ + trow)) * HID_ + hq * HD_ + hj * 16 + grp * 4] = o;
    }
  }
}

// ---------------- launcher ----------------
extern "C" void kernel_launch(void* const* d_in, const int* in_sizes, int n_in,
                              void* d_out, int out_size, void* d_ws, size_t ws_size,
                              hipStream_t stream) {
  const float* x    = (const float*)d_in[0];
  const float* cosb = (const float*)d_in[1];
  const float* sinb = (const float*)d_in[2];
  const float* Wq   = (const float*)d_in[3];
  const float* Wk   = (const float*)d_in[4];
  const float* Wv   = (const float*)d_in[5];
  const float* Wo   = (const float*)d_in[6];
  float* out = (float*)d_out;

  char* ws = (char*)d_ws;
  size_t off = 0;
  auto take = [&](size_t elems) {
    unsigned short* p = (unsigned short*)(ws + off);
    off += ((elems * 2 + 255) & ~(size_t)255);
    return p;
  };
  unsigned short* xb   = take((size_t)M_ * HID_);
  unsigned short* wqkv = take((size_t)NQKV_ * HID_);
  unsigned short* wob  = take((size_t)HID_ * HID_);
  unsigned short* qkv  = take((size_t)M_ * NQKV_);
  unsigned short* qb   = take((size_t)B_ * NH_ * T_ * HD_);
  unsigned short* kb   = take((size_t)B_ * NKV_ * T_ * HD_);
  unsigned short* vb   = take((size_t)B_ * NKV_ * T_ * HD_);
  unsigned short* vtb  = take((size_t)B_ * NKV_ * T_ * HD_);
  unsigned short* yb   = take((size_t)M_ * HID_);
  (void)ws_size; (void)in_sizes; (void)n_in; (void)out_size;

  cast_bf16<<<16384, 256, 0, stream>>>(x, xb, 4194304);
  cast_w<<<5120, 256, 0, stream>>>(Wq, Wk, Wv, wqkv);
  cast_bf16<<<4096, 256, 0, stream>>>(Wo, wob, 1048576);

  gemm_bt<1><<<dim3(20, 64), 256, 0, stream>>>(xb, wqkv, qkv, M_, NQKV_, HID_);
  rope_norm<<<8192, 256, 0, stream>>>(qkv, cosb, sinb, qb, kb, vb);
  transpose_v<<<dim3(32, 2, 8), 256, 0, stream>>>(vb, vtb);
  flash_attn<<<dim3(16, 16, 4), 256, 0, stream>>>(qb, kb, vtb, yb);
  gemm_bt<0><<<dim3(16, 64), 256, 0, stream>>>(yb, wob, out, M_, HID_, HID_);
}